// Round 9
// baseline (216.117 us; speedup 1.0000x reference)
//
#include <hip/hip_runtime.h>
#include <math.h>

#define B_   4
#define N_   512
#define T_   128
#define F_   64
#define QT   128
#define NSTR (T_*F_)   // 8192 floats between consecutive n in x
#define TILE 8192      // bytes per k-tile (fallback kernel LDS layout)

typedef __attribute__((ext_vector_type(8))) short  s8v;
typedef __attribute__((ext_vector_type(4))) float  f4v;

union F8 { s8v v; unsigned u[4]; uint2 u2[2]; };

__device__ __forceinline__ unsigned cvt_pk(float lo, float hi) {
    unsigned r;
    asm("v_cvt_pk_bf16_f32 %0, %1, %2" : "=v"(r) : "v"(lo), "v"(hi));
    return r;
}

template<int OFF>
__device__ __forceinline__ uint2 tr16(unsigned a) {
    uint2 d;
    asm volatile("ds_read_b64_tr_b16 %0, %1 offset:%2" : "=v"(d) : "v"(a), "i"(OFF));
    return d;
}

#define EXPK 0.18033688f   // 0.125 * log2(e) : exp(s/8) = exp2(s*EXPK)

// ---- P1: x[b][n][t][f] (f32) -> xt[b][t][n][f] (bf16)  (validated in R8) ----
__global__ __launch_bounds__(256)
void xpose_kernel(const float* __restrict__ x, unsigned short* __restrict__ xt)
{
    __shared__ char lds[32*1024];

    const int tid = threadIdx.x;
    const int lane = tid & 63;
    const int w    = tid >> 6;
    const int n0 = blockIdx.x * 8;
    const int t0 = blockIdx.y * 32;
    const int b  = blockIdx.z;

    const int tA = tid >> 3;
    const int f0 = (tid & 7) * 8;

    #pragma unroll
    for (int np = 0; np < 8; ++np) {
        const float* gp = x + ((size_t)(b*N_ + n0 + np)*T_ + t0 + tA)*F_ + f0;
        float4 a = *(const float4*)gp;
        float4 c = *(const float4*)(gp + 4);
        uint4 u;
        u.x = cvt_pk(a.x, a.y); u.y = cvt_pk(a.z, a.w);
        u.z = cvt_pk(c.x, c.y); u.w = cvt_pk(c.z, c.w);
        *(uint4*)(lds + tA*1024 + np*128 + ((f0*2) ^ ((tA & 7) << 4))) = u;
    }
    __syncthreads();

    #pragma unroll
    for (int p = 0; p < 8; ++p) {
        int t  = p*4 + w;
        int np = lane >> 3;
        int i  = lane & 7;
        uint4 u = *(const uint4*)(lds + t*1024 + np*128 + ((i*16) ^ ((t & 7) << 4)));
        *(uint4*)(xt + ((size_t)(b*T_ + t0 + t)*N_ + n0 + np)*F_ + i*8) = u;
    }
}

// ---- P2: xt -> xc, V in MFMA-fragment-direct layout (pure permutation) ----
// xc tile (per g,kt; 8192 B): byte = kk*4096 + ft*1024 + fc*64 + g4*16 + s*8 + r*2
// holding V^T element (f = 16ft+fc, n = kt*64 + 32kk + 16s + 4g4 + r).
__global__ __launch_bounds__(256)
void xcpack_kernel(const unsigned short* __restrict__ xt, unsigned short* __restrict__ xc)
{
    __shared__ char lds[8192];
    const int tid = threadIdx.x;
    const int kt  = blockIdx.x;     // 0..7
    const int g   = blockIdx.y;     // 0..511

    const unsigned short* src = xt + ((size_t)g*N_ + kt*64)*F_;
    #pragma unroll
    for (int p = 0; p < 2; ++p) {
        int idx = tid + 256*p;          // 0..511 16B chunks
        int row = idx >> 3, ch = idx & 7;
        uint4 v = *(const uint4*)(src + row*F_ + ch*8);
        *(uint4*)(lds + row*128 + ((ch*16) ^ ((row & 7) << 4))) = v;
    }
    __syncthreads();

    unsigned short* dst = xc + (size_t)g*(N_*F_) + kt*4096;   // u16 units
    #pragma unroll
    for (int p = 0; p < 2; ++p) {
        int idx = tid + 256*p;          // 0..511 output frags
        int kk = idx >> 8, ft = (idx >> 6) & 3, fc = (idx >> 2) & 15, g4 = idx & 3;
        int f2 = (16*ft + fc)*2;
        unsigned short e[8];
        #pragma unroll
        for (int s = 0; s < 2; ++s)
          #pragma unroll
          for (int r = 0; r < 4; ++r) {
            int n = 32*kk + 16*s + 4*g4 + r;
            e[s*4+r] = *(const unsigned short*)(lds + n*128 + (f2 ^ ((n & 7) << 4)));
          }
        uint4 o;
        o.x = e[0] | ((unsigned)e[1] << 16);
        o.y = e[2] | ((unsigned)e[3] << 16);
        o.z = e[4] | ((unsigned)e[5] << 16);
        o.w = e[6] | ((unsigned)e[7] << 16);
        *(uint4*)(dst + idx*8) = o;
    }
}

// ---- main: zero LDS, zero barriers ----
__global__ __launch_bounds__(256, 4)
void sgcn_nolds_kernel(const unsigned short* __restrict__ xt,
                       const unsigned short* __restrict__ xc,
                       const float* __restrict__ adj,
                       const float* __restrict__ theta,
                       float* __restrict__ out)
{
    const int tid  = threadIdx.x;
    const int lane = tid & 63;
    const int w    = tid >> 6;
    const int c15  = lane & 15;
    const int g4   = lane >> 4;

    // XCD-bijective swizzle: 4 sibling q-blocks of a group land on one XCD
    const int bid = blockIdx.x;            // 0..2047
    const int g   = (bid & 7)*64 + (bid >> 5);
    const int qx  = (bid >> 3) & 3;
    const int b   = g >> 7;
    const int t   = g & 127;
    const int q0  = qx*QT + 32*w;

    const unsigned short* xtg = xt + (size_t)g*N_*F_;
    const unsigned short* xcg = xc + (size_t)g*N_*F_;

    // Q B-frags (swapped QK): f-map f = 32kk + 8g4 + j
    F8 qf[2][2];
    #pragma unroll
    for (int qt = 0; qt < 2; ++qt)
      #pragma unroll
      for (int kk = 0; kk < 2; ++kk)
        qf[qt][kk].v = *(const s8v*)(xtg + (size_t)(q0 + 16*qt + c15)*F_ + 32*kk + 8*g4);

    f4v  Oacc[4][2];
    float l_acc[2] = {0.f, 0.f};
    #pragma unroll
    for (int ft = 0; ft < 4; ++ft)
      #pragma unroll
      for (int qt = 0; qt < 2; ++qt) Oacc[ft][qt] = (f4v)0.f;

    const float* arow0 = adj + (size_t)(q0 +      c15)*N_ + 4*g4;
    const float* arow1 = adj + (size_t)(q0 + 16 + c15)*N_ + 4*g4;

    for (int kt = 0; kt < 8; ++kt) {
        const unsigned short* kb = xtg + (size_t)(kt*64 + c15)*F_ + 8*g4;
        const unsigned short* vb = xcg + kt*4096 + c15*32 + g4*8;   // u16 units

        // ---- QK^T + softmax, per mt ----
        F8 pb[2][2];   // slot j: m = 32kk + 16*(j>=4) + 4g4 + (j&3)
        #pragma unroll
        for (int mt = 0; mt < 4; ++mt) {
            F8 af0, af1;   // A: row m = 16mt+c15, k-slot j -> f = 32kk+8g4+j
            af0.v = *(const s8v*)(kb + mt*16*F_);
            af1.v = *(const s8v*)(kb + mt*16*F_ + 32);
            float4 av0 = *(const float4*)(arow0 + kt*64 + 16*mt);
            float4 av1 = *(const float4*)(arow1 + kt*64 + 16*mt);

            #pragma unroll
            for (int qt = 0; qt < 2; ++qt) {
                f4v s = (f4v)0.f;
                s = __builtin_amdgcn_mfma_f32_16x16x32_bf16(af0.v, qf[qt][0].v, s, 0, 0, 0);
                s = __builtin_amdgcn_mfma_f32_16x16x32_bf16(af1.v, qf[qt][1].v, s, 0, 0, 0);
                float e0 = __builtin_amdgcn_exp2f(s[0] * EXPK);
                float e1 = __builtin_amdgcn_exp2f(s[1] * EXPK);
                float e2 = __builtin_amdgcn_exp2f(s[2] * EXPK);
                float e3 = __builtin_amdgcn_exp2f(s[3] * EXPK);
                l_acc[qt] += (e0 + e1) + (e2 + e3);
                float4 av = qt ? av1 : av0;
                pb[qt][mt>>1].u[2*(mt&1)  ] = cvt_pk(e0*av.x, e1*av.y);
                pb[qt][mt>>1].u[2*(mt&1)+1] = cvt_pk(e2*av.z, e3*av.w);
            }
        }

        // ---- PV: V^T A-frags are single coalesced 16B global loads ----
        #pragma unroll
        for (int kk = 0; kk < 2; ++kk)
          #pragma unroll
          for (int ft = 0; ft < 4; ++ft) {
            F8 vf;
            vf.v = *(const s8v*)(vb + kk*2048 + ft*512);
            #pragma unroll
            for (int qt = 0; qt < 2; ++qt)
              Oacc[ft][qt] = __builtin_amdgcn_mfma_f32_16x16x32_bf16(vf.v, pb[qt][kk].v, Oacc[ft][qt], 0, 0, 0);
          }
    }

    // ---- softmax denominators ----
    float inv[2];
    #pragma unroll
    for (int qt = 0; qt < 2; ++qt) {
        float lv = l_acc[qt];
        lv += __shfl_xor(lv, 16);
        lv += __shfl_xor(lv, 32);
        inv[qt] = 0.125f / lv;
    }

    // ---- B-frags from O^T (lane-local), scaled ----
    F8 ob[2][2];
    #pragma unroll
    for (int qt = 0; qt < 2; ++qt)
      #pragma unroll
      for (int kk = 0; kk < 2; ++kk) {
        f4v o0 = Oacc[2*kk][qt], o1 = Oacc[2*kk+1][qt];
        ob[qt][kk].u[0] = cvt_pk(o0[0]*inv[qt], o0[1]*inv[qt]);
        ob[qt][kk].u[1] = cvt_pk(o0[2]*inv[qt], o0[3]*inv[qt]);
        ob[qt][kk].u[2] = cvt_pk(o1[0]*inv[qt], o1[1]*inv[qt]);
        ob[qt][kk].u[3] = cvt_pk(o1[2]*inv[qt], o1[3]*inv[qt]);
      }

    // ---- Theta A-frags ----
    F8 tf[4][2];
    #pragma unroll
    for (int ot = 0; ot < 4; ++ot)
      #pragma unroll
      for (int kk = 0; kk < 2; ++kk) {
        const float* tp = theta + (size_t)(16*ot + c15)*F_ + 32*kk + 4*g4;
        float4 a = *(const float4*)tp;
        float4 c = *(const float4*)(tp + 16);
        tf[ot][kk].u[0] = cvt_pk(a.x, a.y);
        tf[ot][kk].u[1] = cvt_pk(a.z, a.w);
        tf[ot][kk].u[2] = cvt_pk(c.x, c.y);
        tf[ot][kk].u[3] = cvt_pk(c.z, c.w);
      }

    // ---- R^T = Theta * (O^T * inv), relu, store ----
    f4v R[4][2];
    #pragma unroll
    for (int ot = 0; ot < 4; ++ot)
      #pragma unroll
      for (int qt = 0; qt < 2; ++qt) R[ot][qt] = (f4v)0.f;

    #pragma unroll
    for (int kk = 0; kk < 2; ++kk)
      #pragma unroll
      for (int ot = 0; ot < 4; ++ot)
        #pragma unroll
        for (int qt = 0; qt < 2; ++qt)
          R[ot][qt] = __builtin_amdgcn_mfma_f32_16x16x32_bf16(tf[ot][kk].v, ob[qt][kk].v, R[ot][qt], 0, 0, 0);

    #pragma unroll
    for (int ot = 0; ot < 4; ++ot)
      #pragma unroll
      for (int qt = 0; qt < 2; ++qt) {
        float4 v;
        v.x = fmaxf(R[ot][qt][0], 0.f);
        v.y = fmaxf(R[ot][qt][1], 0.f);
        v.z = fmaxf(R[ot][qt][2], 0.f);
        v.w = fmaxf(R[ot][qt][3], 0.f);
        int q  = q0 + 16*qt + c15;
        int fo = 16*ot + 4*g4;
        *(float4*)(out + ((size_t)(b*N_ + q)*T_ + t)*F_ + fo) = v;
      }
}

// ---- fallback (R8 kernel, self-contained, no workspace) ----
__global__ __launch_bounds__(256, 3)
void sgcn_fb_kernel(const float* __restrict__ x,
                    const float* __restrict__ adj,
                    const float* __restrict__ theta,
                    float* __restrict__ out)
{
    __shared__ char ldsbuf[2*TILE];

    const int tid  = threadIdx.x;
    const int lane = tid & 63;
    const int w    = tid >> 6;
    const int c15  = lane & 15;
    const int g4   = lane >> 4;

    const int g  = blockIdx.y;
    const int b  = g >> 7;
    const int t  = g & 127;
    const int q0 = blockIdx.x*QT + 32*w;

    const float* xg = x + (size_t)b*N_*NSTR + (size_t)t*F_;

    F8 qf[2][2];
    #pragma unroll
    for (int qt = 0; qt < 2; ++qt)
      #pragma unroll
      for (int kk = 0; kk < 2; ++kk) {
        const float* qp = xg + (size_t)(q0 + 16*qt + c15)*NSTR + 32*kk + 8*g4;
        float4 a = *(const float4*)qp;
        float4 c = *(const float4*)(qp + 4);
        qf[qt][kk].u[0] = cvt_pk(a.x, a.y);
        qf[qt][kk].u[1] = cvt_pk(a.z, a.w);
        qf[qt][kk].u[2] = cvt_pk(c.x, c.y);
        qf[qt][kk].u[3] = cvt_pk(c.z, c.w);
      }

    f4v  Oacc[4][2];
    float l_acc[2] = {0.f, 0.f};
    #pragma unroll
    for (int ft = 0; ft < 4; ++ft)
      #pragma unroll
      for (int qt = 0; qt < 2; ++qt) Oacc[ft][qt] = (f4v)0.f;

    const int nrow  = tid >> 4;
    const int stoff = (c15>>2)*2048 + w*128 + g4*32 + (c15&3)*8;
    const int afoff = (g4>>1)*2048 + (c15>>2)*128 + (c15&3)*32 + (g4&1)*16;

    const float* arow0 = adj + (size_t)(q0 +      c15)*N_ + 4*g4;
    const float* arow1 = adj + (size_t)(q0 + 16 + c15)*N_ + 4*g4;

    float4 xv[4];
    auto stage = [&](char* buf) {
        #pragma unroll
        for (int it = 0; it < 4; ++it) {
            unsigned p0 = cvt_pk(xv[it].x, xv[it].y);
            unsigned p1 = cvt_pk(xv[it].z, xv[it].w);
            *(uint2*)(buf + stoff + it*512) = make_uint2(p0, p1);
        }
    };
    auto loadK = [&](int k0) {
        #pragma unroll
        for (int it = 0; it < 4; ++it)
            xv[it] = *(const float4*)(xg + (size_t)(k0 + nrow + 16*it)*NSTR + 4*c15);
    };

    loadK(0);
    stage(ldsbuf);
    const unsigned xb = (unsigned)(uintptr_t)ldsbuf;

    for (int kt = 0; kt < 8; ++kt) {
        __syncthreads();
        char* bufC = ldsbuf + (size_t)(kt & 1) * TILE;
        char* bufN = ldsbuf + (size_t)((kt & 1) ^ 1) * TILE;
        if (kt < 7) loadK((kt+1)*64);

        F8 pb[2][2];
        #pragma unroll
        for (int mt = 0; mt < 4; ++mt) {
            float4 av0 = *(const float4*)(arow0 + kt*64 + 16*mt);
            float4 av1 = *(const float4*)(arow1 + kt*64 + 16*mt);
            F8 af0, af1;
            af0.v = *(const s8v*)(bufC + afoff + mt*512);
            af1.v = *(const s8v*)(bufC + afoff + mt*512 + 4096);
            #pragma unroll
            for (int qt = 0; qt < 2; ++qt) {
                f4v s = (f4v)0.f;
                s = __builtin_amdgcn_mfma_f32_16x16x32_bf16(af0.v, qf[qt][0].v, s, 0, 0, 0);
                s = __builtin_amdgcn_mfma_f32_16x16x32_bf16(af1.v, qf[qt][1].v, s, 0, 0, 0);
                float e0 = __builtin_amdgcn_exp2f(s[0] * EXPK);
                float e1 = __builtin_amdgcn_exp2f(s[1] * EXPK);
                float e2 = __builtin_amdgcn_exp2f(s[2] * EXPK);
                float e3 = __builtin_amdgcn_exp2f(s[3] * EXPK);
                l_acc[qt] += (e0 + e1) + (e2 + e3);
                float4 av = qt ? av1 : av0;
                pb[qt][mt>>1].u[2*(mt&1)  ] = cvt_pk(e0*av.x, e1*av.y);
                pb[qt][mt>>1].u[2*(mt&1)+1] = cvt_pk(e2*av.z, e3*av.w);
            }
        }

        const unsigned va = xb + (unsigned)((kt & 1) * TILE) + (unsigned)(lane * 8);
        {
            F8 vf0, vf1, vf2, vf3;
            vf0.u2[0] = tr16<   0>(va); vf0.u2[1] = tr16< 512>(va);
            vf1.u2[0] = tr16<2048>(va); vf1.u2[1] = tr16<2560>(va);
            vf2.u2[0] = tr16<4096>(va); vf2.u2[1] = tr16<4608>(va);
            vf3.u2[0] = tr16<6144>(va); vf3.u2[1] = tr16<6656>(va);
            asm volatile("s_waitcnt lgkmcnt(0)" ::: "memory");
            __builtin_amdgcn_sched_barrier(0);
            #pragma unroll
            for (int qt = 0; qt < 2; ++qt) {
                Oacc[0][qt] = __builtin_amdgcn_mfma_f32_16x16x32_bf16(vf0.v, pb[qt][0].v, Oacc[0][qt], 0, 0, 0);
                Oacc[1][qt] = __builtin_amdgcn_mfma_f32_16x16x32_bf16(vf1.v, pb[qt][0].v, Oacc[1][qt], 0, 0, 0);
                Oacc[2][qt] = __builtin_amdgcn_mfma_f32_16x16x32_bf16(vf2.v, pb[qt][0].v, Oacc[2][qt], 0, 0, 0);
                Oacc[3][qt] = __builtin_amdgcn_mfma_f32_16x16x32_bf16(vf3.v, pb[qt][0].v, Oacc[3][qt], 0, 0, 0);
            }
        }
        {
            F8 vf0, vf1, vf2, vf3;
            vf0.u2[0] = tr16<1024>(va); vf0.u2[1] = tr16<1536>(va);
            vf1.u2[0] = tr16<3072>(va); vf1.u2[1] = tr16<3584>(va);
            vf2.u2[0] = tr16<5120>(va); vf2.u2[1] = tr16<5632>(va);
            vf3.u2[0] = tr16<7168>(va); vf3.u2[1] = tr16<7680>(va);
            asm volatile("s_waitcnt lgkmcnt(0)" ::: "memory");
            __builtin_amdgcn_sched_barrier(0);
            #pragma unroll
            for (int qt = 0; qt < 2; ++qt) {
                Oacc[0][qt] = __builtin_amdgcn_mfma_f32_16x16x32_bf16(vf0.v, pb[qt][1].v, Oacc[0][qt], 0, 0, 0);
                Oacc[1][qt] = __builtin_amdgcn_mfma_f32_16x16x32_bf16(vf1.v, pb[qt][1].v, Oacc[1][qt], 0, 0, 0);
                Oacc[2][qt] = __builtin_amdgcn_mfma_f32_16x16x32_bf16(vf2.v, pb[qt][1].v, Oacc[2][qt], 0, 0, 0);
                Oacc[3][qt] = __builtin_amdgcn_mfma_f32_16x16x32_bf16(vf3.v, pb[qt][1].v, Oacc[3][qt], 0, 0, 0);
            }
        }
        if (kt < 7) stage(bufN);
    }

    float inv[2];
    #pragma unroll
    for (int qt = 0; qt < 2; ++qt) {
        float lv = l_acc[qt];
        lv += __shfl_xor(lv, 16);
        lv += __shfl_xor(lv, 32);
        inv[qt] = 0.125f / lv;
    }

    F8 ob[2][2];
    #pragma unroll
    for (int qt = 0; qt < 2; ++qt)
      #pragma unroll
      for (int kk = 0; kk < 2; ++kk) {
        f4v o0 = Oacc[2*kk][qt], o1 = Oacc[2*kk+1][qt];
        ob[qt][kk].u[0] = cvt_pk(o0[0]*inv[qt], o0[1]*inv[qt]);
        ob[qt][kk].u[1] = cvt_pk(o0[2]*inv[qt], o0[3]*inv[qt]);
        ob[qt][kk].u[2] = cvt_pk(o1[0]*inv[qt], o1[1]*inv[qt]);
        ob[qt][kk].u[3] = cvt_pk(o1[2]*inv[qt], o1[3]*inv[qt]);
      }

    F8 tf[4][2];
    #pragma unroll
    for (int ot = 0; ot < 4; ++ot)
      #pragma unroll
      for (int kk = 0; kk < 2; ++kk) {
        const float* tp = theta + (size_t)(16*ot + c15)*F_ + 32*kk + 4*g4;
        float4 a = *(const float4*)tp;
        float4 c = *(const float4*)(tp + 16);
        tf[ot][kk].u[0] = cvt_pk(a.x, a.y);
        tf[ot][kk].u[1] = cvt_pk(a.z, a.w);
        tf[ot][kk].u[2] = cvt_pk(c.x, c.y);
        tf[ot][kk].u[3] = cvt_pk(c.z, c.w);
      }

    f4v R[4][2];
    #pragma unroll
    for (int ot = 0; ot < 4; ++ot)
      #pragma unroll
      for (int qt = 0; qt < 2; ++qt) R[ot][qt] = (f4v)0.f;

    #pragma unroll
    for (int kk = 0; kk < 2; ++kk)
      #pragma unroll
      for (int ot = 0; ot < 4; ++ot)
        #pragma unroll
        for (int qt = 0; qt < 2; ++qt)
          R[ot][qt] = __builtin_amdgcn_mfma_f32_16x16x32_bf16(tf[ot][kk].v, ob[qt][kk].v, R[ot][qt], 0, 0, 0);

    #pragma unroll
    for (int ot = 0; ot < 4; ++ot)
      #pragma unroll
      for (int qt = 0; qt < 2; ++qt) {
        float4 v;
        v.x = fmaxf(R[ot][qt][0], 0.f);
        v.y = fmaxf(R[ot][qt][1], 0.f);
        v.z = fmaxf(R[ot][qt][2], 0.f);
        v.w = fmaxf(R[ot][qt][3], 0.f);
        int q  = q0 + 16*qt + c15;
        int fo = 16*ot + 4*g4;
        *(float4*)(out + ((size_t)(b*N_ + q)*T_ + t)*F_ + fo) = v;
      }
}

extern "C" void kernel_launch(void* const* d_in, const int* in_sizes, int n_in,
                              void* d_out, int out_size, void* d_ws, size_t ws_size,
                              hipStream_t stream) {
    const float* x     = (const float*)d_in[0];
    const float* adj   = (const float*)d_in[1];
    const float* theta = (const float*)d_in[2];
    float* out = (float*)d_out;

    const size_t one = (size_t)B_*T_*N_*F_*2;   // 33.5 MB
    if (ws_size >= 2*one) {
        unsigned short* xt = (unsigned short*)d_ws;
        unsigned short* xc = xt + (size_t)B_*T_*N_*F_;
        xpose_kernel <<<dim3(N_/8, T_/32, B_), 256, 0, stream>>>(x, xt);
        xcpack_kernel<<<dim3(8, B_*T_),        256, 0, stream>>>(xt, xc);
        sgcn_nolds_kernel<<<2048, 256, 0, stream>>>(xt, xc, adj, theta, out);
    } else {
        dim3 grid(N_ / QT, B_ * T_);
        sgcn_fb_kernel<<<grid, 256, 0, stream>>>(x, adj, theta, out);
    }
}

// Round 10
// 131.274 us; speedup vs baseline: 1.6463x; 1.6463x over previous
//
#include <hip/hip_runtime.h>
#include <math.h>

#define B_   4
#define N_   512
#define T_   128
#define F_   64
#define QB   128       // q rows per block
#define NSTR (T_*F_)   // 8192 floats between consecutive n in x
#define TILE 8192      // bytes per K tile (blocked layout)
// blocked tile layout: byte(n,f) = (f>>4)*2048 + (n>>2)*128 + (n&3)*32 + (f&15)*2

typedef __attribute__((ext_vector_type(8))) short  s8v;
typedef __attribute__((ext_vector_type(4))) float  f4v;

union F8 { s8v v; unsigned u[4]; uint2 u2[2]; };

__device__ __forceinline__ unsigned cvt_pk(float lo, float hi) {
    unsigned r;
    asm("v_cvt_pk_bf16_f32 %0, %1, %2" : "=v"(r) : "v"(lo), "v"(hi));
    return r;
}

template<int OFF>
__device__ __forceinline__ uint2 tr16(unsigned a) {
    uint2 d;
    asm volatile("ds_read_b64_tr_b16 %0, %1 offset:%2" : "=v"(d) : "v"(a), "i"(OFF));
    return d;
}

__device__ __forceinline__ void gload16(const void* g, void* l) {
    __builtin_amdgcn_global_load_lds(
        (const __attribute__((address_space(1))) void*)g,
        (__attribute__((address_space(3))) void*)l, 16, 0, 0);
}

#define EXPK 0.18033688f   // 0.125 * log2(e)

// ---- P1: x[b][n][t][f] (f32) -> xt[b][t][n][f] (bf16)  (validated R8) ----
__global__ __launch_bounds__(256)
void xpose_kernel(const float* __restrict__ x, unsigned short* __restrict__ xt)
{
    __shared__ char lds[32*1024];

    const int tid = threadIdx.x;
    const int lane = tid & 63;
    const int w    = tid >> 6;
    const int n0 = blockIdx.x * 8;
    const int t0 = blockIdx.y * 32;
    const int b  = blockIdx.z;

    const int tA = tid >> 3;
    const int f0 = (tid & 7) * 8;

    #pragma unroll
    for (int np = 0; np < 8; ++np) {
        const float* gp = x + ((size_t)(b*N_ + n0 + np)*T_ + t0 + tA)*F_ + f0;
        float4 a = *(const float4*)gp;
        float4 c = *(const float4*)(gp + 4);
        uint4 u;
        u.x = cvt_pk(a.x, a.y); u.y = cvt_pk(a.z, a.w);
        u.z = cvt_pk(c.x, c.y); u.w = cvt_pk(c.z, c.w);
        *(uint4*)(lds + tA*1024 + np*128 + ((f0*2) ^ ((tA & 7) << 4))) = u;
    }
    __syncthreads();

    #pragma unroll
    for (int p = 0; p < 8; ++p) {
        int t  = p*4 + w;
        int np = lane >> 3;
        int i  = lane & 7;
        uint4 u = *(const uint4*)(lds + t*1024 + np*128 + ((i*16) ^ ((t & 7) << 4)));
        *(uint4*)(xt + ((size_t)(b*T_ + t0 + t)*N_ + n0 + np)*F_ + i*8) = u;
    }
}

// ---- main: 2 groups/block share one LDS adj tile; K staged via global_load_lds ----
__global__ __launch_bounds__(512, 4)
void sgcn_shadj_kernel(const unsigned short* __restrict__ xt,
                       const float* __restrict__ adj,
                       const float* __restrict__ theta,
                       float* __restrict__ out)
{
    __shared__ char lds[65536];   // [0,32K): K tiles (2 streams x dbuf x 8K); [32K,64K): adj tile

    const int tid  = threadIdx.x;
    const int lane = tid & 63;
    const int w    = tid >> 6;     // 0..7
    const int s    = w >> 2;       // stream (group) 0/1
    const int wq   = w & 3;        // q sub-tile within block
    const int c15  = lane & 15;
    const int g4   = lane >> 4;

    const int bid = blockIdx.x;    // 0..1023
    const int qx  = bid & 3;
    const int tp  = bid >> 2;
    const int g   = 2*tp + s;      // this wave's group
    const int b   = g >> 7;
    const int t   = g & 127;
    const int qb  = qx*QB;
    const int q0  = qb + 32*wq;

    const unsigned short* xtg = xt + (size_t)g*N_*F_;
    char* Kbase = lds + s*(2*TILE);
    char* Abase = lds + 32768;

    // ---- Q B-frags (swapped QK): f = 32kk + 8g4 + j ----
    F8 qf[2][2];
    #pragma unroll
    for (int qt = 0; qt < 2; ++qt)
      #pragma unroll
      for (int kk = 0; kk < 2; ++kk)
        qf[qt][kk].v = *(const s8v*)(xtg + (size_t)(q0 + 16*qt + c15)*F_ + 32*kk + 8*g4);

    f4v  Oacc[4][2];
    float l_acc[2] = {0.f, 0.f};
    #pragma unroll
    for (int ft = 0; ft < 4; ++ft)
      #pragma unroll
      for (int qt = 0; qt < 2; ++qt) Oacc[ft][qt] = (f4v)0.f;

    // gload_lds source offsets: chunk c -> (n, f0) of blocked layout
    int soff[2];
    #pragma unroll
    for (int i = 0; i < 2; ++i) {
        int c  = wq*128 + i*64 + lane;
        int fh = c >> 7, r = c & 127;
        int nh = r >> 3, r2 = r & 7;
        int n  = nh*4 + (r2 >> 1);
        int f0 = fh*16 + (r2 & 1)*8;
        soff[i] = n*F_ + f0;
    }

    float4 areg[4];
    auto adjLoad = [&](int kt1) {
        #pragma unroll
        for (int i = 0; i < 4; ++i) {
            int li = tid + 512*i, row = li >> 4, cc = li & 15;
            areg[i] = *(const float4*)(adj + (size_t)(qb + row)*N_ + kt1*64 + cc*4);
        }
    };
    auto adjWrite = [&]() {
        #pragma unroll
        for (int i = 0; i < 4; ++i) {
            int li = tid + 512*i, row = li >> 4, cc = li & 15;
            *(float4*)(Abase + row*256 + ((cc ^ (row & 15)) << 4)) = areg[i];
        }
    };
    auto stageK = [&](int kt1, int p) {
        const unsigned short* sb = xtg + (size_t)kt1*64*F_;
        #pragma unroll
        for (int i = 0; i < 2; ++i)
            gload16(sb + soff[i], Kbase + p*TILE + (wq*128 + i*64)*16);
    };

    // QK A-frag byte addr: afoff + mt*512 + kk*4096 -> m = 16mt+c15, f = 32kk+8g4+j
    const int afoff = (g4>>1)*2048 + (c15>>2)*128 + (c15&3)*32 + (g4&1)*16;

    // ---- prologue ----
    stageK(0, 0);
    adjLoad(0);
    adjWrite();

    for (int kt = 0; kt < 8; ++kt) {
        __syncthreads();   // K[kt] (vmcnt drained) + adj[kt] (lgkm) published

        const char* bufC = Kbase + (size_t)(kt & 1)*TILE;
        if (kt < 7) {
            stageK(kt+1, (kt+1) & 1);   // async direct-to-LDS, other buffer
            adjLoad(kt+1);              // -> regs, written after mid-barrier
        }

        // ---- QK^T + softmax (adj from shared LDS tile) ----
        F8 pb[2][2];   // slot j: m = 32kk + 16*(j>=4) + 4g4 + (j&3)
        #pragma unroll
        for (int mt = 0; mt < 4; ++mt) {
            const int cc = 4*mt + g4;
            const int r0a = 32*wq + c15;
            const int r1a = r0a + 16;
            float4 av0 = *(const float4*)(Abase + r0a*256 + ((cc ^ (r0a & 15)) << 4));
            float4 av1 = *(const float4*)(Abase + r1a*256 + ((cc ^ (r1a & 15)) << 4));

            F8 af0, af1;
            af0.v = *(const s8v*)(bufC + afoff + mt*512);
            af1.v = *(const s8v*)(bufC + afoff + mt*512 + 4096);

            #pragma unroll
            for (int qt = 0; qt < 2; ++qt) {
                f4v sv = (f4v)0.f;
                sv = __builtin_amdgcn_mfma_f32_16x16x32_bf16(af0.v, qf[qt][0].v, sv, 0, 0, 0);
                sv = __builtin_amdgcn_mfma_f32_16x16x32_bf16(af1.v, qf[qt][1].v, sv, 0, 0, 0);
                float e0 = __builtin_amdgcn_exp2f(sv[0] * EXPK);
                float e1 = __builtin_amdgcn_exp2f(sv[1] * EXPK);
                float e2 = __builtin_amdgcn_exp2f(sv[2] * EXPK);
                float e3 = __builtin_amdgcn_exp2f(sv[3] * EXPK);
                l_acc[qt] += (e0 + e1) + (e2 + e3);
                float4 av = qt ? av1 : av0;
                pb[qt][mt>>1].u[2*(mt&1)  ] = cvt_pk(e0*av.x, e1*av.y);
                pb[qt][mt>>1].u[2*(mt&1)+1] = cvt_pk(e2*av.z, e3*av.w);
            }
        }

        // ---- PV via hardware transpose reads (layout validated R8) ----
        const unsigned va = (unsigned)(uintptr_t)bufC + (unsigned)(lane * 8);
        {
            F8 vf0, vf1, vf2, vf3;
            vf0.u2[0] = tr16<   0>(va); vf0.u2[1] = tr16< 512>(va);
            vf1.u2[0] = tr16<2048>(va); vf1.u2[1] = tr16<2560>(va);
            vf2.u2[0] = tr16<4096>(va); vf2.u2[1] = tr16<4608>(va);
            vf3.u2[0] = tr16<6144>(va); vf3.u2[1] = tr16<6656>(va);
            asm volatile("s_waitcnt lgkmcnt(0)" ::: "memory");
            __builtin_amdgcn_sched_barrier(0);
            #pragma unroll
            for (int qt = 0; qt < 2; ++qt) {
                Oacc[0][qt] = __builtin_amdgcn_mfma_f32_16x16x32_bf16(vf0.v, pb[qt][0].v, Oacc[0][qt], 0, 0, 0);
                Oacc[1][qt] = __builtin_amdgcn_mfma_f32_16x16x32_bf16(vf1.v, pb[qt][0].v, Oacc[1][qt], 0, 0, 0);
                Oacc[2][qt] = __builtin_amdgcn_mfma_f32_16x16x32_bf16(vf2.v, pb[qt][0].v, Oacc[2][qt], 0, 0, 0);
                Oacc[3][qt] = __builtin_amdgcn_mfma_f32_16x16x32_bf16(vf3.v, pb[qt][0].v, Oacc[3][qt], 0, 0, 0);
            }
        }
        {
            F8 vf0, vf1, vf2, vf3;
            vf0.u2[0] = tr16<1024>(va); vf0.u2[1] = tr16<1536>(va);
            vf1.u2[0] = tr16<3072>(va); vf1.u2[1] = tr16<3584>(va);
            vf2.u2[0] = tr16<5120>(va); vf2.u2[1] = tr16<5632>(va);
            vf3.u2[0] = tr16<7168>(va); vf3.u2[1] = tr16<7680>(va);
            asm volatile("s_waitcnt lgkmcnt(0)" ::: "memory");
            __builtin_amdgcn_sched_barrier(0);
            #pragma unroll
            for (int qt = 0; qt < 2; ++qt) {
                Oacc[0][qt] = __builtin_amdgcn_mfma_f32_16x16x32_bf16(vf0.v, pb[qt][1].v, Oacc[0][qt], 0, 0, 0);
                Oacc[1][qt] = __builtin_amdgcn_mfma_f32_16x16x32_bf16(vf1.v, pb[qt][1].v, Oacc[1][qt], 0, 0, 0);
                Oacc[2][qt] = __builtin_amdgcn_mfma_f32_16x16x32_bf16(vf2.v, pb[qt][1].v, Oacc[2][qt], 0, 0, 0);
                Oacc[3][qt] = __builtin_amdgcn_mfma_f32_16x16x32_bf16(vf3.v, pb[qt][1].v, Oacc[3][qt], 0, 0, 0);
            }
        }

        if (kt < 7) {
            __syncthreads();   // all waves done reading adj[kt]
            adjWrite();        // publish adj[kt+1] (visible after top barrier)
        }
    }

    // ---- softmax denominators ----
    float inv[2];
    #pragma unroll
    for (int qt = 0; qt < 2; ++qt) {
        float lv = l_acc[qt];
        lv += __shfl_xor(lv, 16);
        lv += __shfl_xor(lv, 32);
        inv[qt] = 0.125f / lv;
    }

    // ---- B-frags from O^T (lane-local), scaled ----
    F8 ob[2][2];
    #pragma unroll
    for (int qt = 0; qt < 2; ++qt)
      #pragma unroll
      for (int kk = 0; kk < 2; ++kk) {
        f4v o0 = Oacc[2*kk][qt], o1 = Oacc[2*kk+1][qt];
        ob[qt][kk].u[0] = cvt_pk(o0[0]*inv[qt], o0[1]*inv[qt]);
        ob[qt][kk].u[1] = cvt_pk(o0[2]*inv[qt], o0[3]*inv[qt]);
        ob[qt][kk].u[2] = cvt_pk(o1[0]*inv[qt], o1[1]*inv[qt]);
        ob[qt][kk].u[3] = cvt_pk(o1[2]*inv[qt], o1[3]*inv[qt]);
      }

    // ---- Theta A-frags ----
    F8 tf[4][2];
    #pragma unroll
    for (int ot = 0; ot < 4; ++ot)
      #pragma unroll
      for (int kk = 0; kk < 2; ++kk) {
        const float* tp2 = theta + (size_t)(16*ot + c15)*F_ + 32*kk + 4*g4;
        float4 a = *(const float4*)tp2;
        float4 c = *(const float4*)(tp2 + 16);
        tf[ot][kk].u[0] = cvt_pk(a.x, a.y);
        tf[ot][kk].u[1] = cvt_pk(a.z, a.w);
        tf[ot][kk].u[2] = cvt_pk(c.x, c.y);
        tf[ot][kk].u[3] = cvt_pk(c.z, c.w);
      }

    // ---- R^T = Theta * (O^T * inv), relu, store ----
    f4v R[4][2];
    #pragma unroll
    for (int ot = 0; ot < 4; ++ot)
      #pragma unroll
      for (int qt = 0; qt < 2; ++qt) R[ot][qt] = (f4v)0.f;

    #pragma unroll
    for (int kk = 0; kk < 2; ++kk)
      #pragma unroll
      for (int ot = 0; ot < 4; ++ot)
        #pragma unroll
        for (int qt = 0; qt < 2; ++qt)
          R[ot][qt] = __builtin_amdgcn_mfma_f32_16x16x32_bf16(tf[ot][kk].v, ob[qt][kk].v, R[ot][qt], 0, 0, 0);

    #pragma unroll
    for (int ot = 0; ot < 4; ++ot)
      #pragma unroll
      for (int qt = 0; qt < 2; ++qt) {
        float4 v;
        v.x = fmaxf(R[ot][qt][0], 0.f);
        v.y = fmaxf(R[ot][qt][1], 0.f);
        v.z = fmaxf(R[ot][qt][2], 0.f);
        v.w = fmaxf(R[ot][qt][3], 0.f);
        int q  = q0 + 16*qt + c15;
        int fo = 16*ot + 4*g4;
        *(float4*)(out + ((size_t)(b*N_ + q)*T_ + t)*F_ + fo) = v;
      }
}

// ---- fallback (R8 kernel, self-contained, validated) ----
__global__ __launch_bounds__(256, 3)
void sgcn_fb_kernel(const float* __restrict__ x,
                    const float* __restrict__ adj,
                    const float* __restrict__ theta,
                    float* __restrict__ out)
{
    __shared__ char ldsbuf[2*TILE];

    const int tid  = threadIdx.x;
    const int lane = tid & 63;
    const int w    = tid >> 6;
    const int c15  = lane & 15;
    const int g4   = lane >> 4;

    const int g  = blockIdx.y;
    const int b  = g >> 7;
    const int t  = g & 127;
    const int q0 = blockIdx.x*QB + 32*w;

    const float* xg = x + (size_t)b*N_*NSTR + (size_t)t*F_;

    F8 qf[2][2];
    #pragma unroll
    for (int qt = 0; qt < 2; ++qt)
      #pragma unroll
      for (int kk = 0; kk < 2; ++kk) {
        const float* qp = xg + (size_t)(q0 + 16*qt + c15)*NSTR + 32*kk + 8*g4;
        float4 a = *(const float4*)qp;
        float4 c = *(const float4*)(qp + 4);
        qf[qt][kk].u[0] = cvt_pk(a.x, a.y);
        qf[qt][kk].u[1] = cvt_pk(a.z, a.w);
        qf[qt][kk].u[2] = cvt_pk(c.x, c.y);
        qf[qt][kk].u[3] = cvt_pk(c.z, c.w);
      }

    f4v  Oacc[4][2];
    float l_acc[2] = {0.f, 0.f};
    #pragma unroll
    for (int ft = 0; ft < 4; ++ft)
      #pragma unroll
      for (int qt = 0; qt < 2; ++qt) Oacc[ft][qt] = (f4v)0.f;

    const int nrow  = tid >> 4;
    const int stoff = (c15>>2)*2048 + w*128 + g4*32 + (c15&3)*8;
    const int afoff = (g4>>1)*2048 + (c15>>2)*128 + (c15&3)*32 + (g4&1)*16;

    const float* arow0 = adj + (size_t)(q0 +      c15)*N_ + 4*g4;
    const float* arow1 = adj + (size_t)(q0 + 16 + c15)*N_ + 4*g4;

    float4 xv[4];
    auto stage = [&](char* buf) {
        #pragma unroll
        for (int it = 0; it < 4; ++it) {
            unsigned p0 = cvt_pk(xv[it].x, xv[it].y);
            unsigned p1 = cvt_pk(xv[it].z, xv[it].w);
            *(uint2*)(buf + stoff + it*512) = make_uint2(p0, p1);
        }
    };
    auto loadK = [&](int k0) {
        #pragma unroll
        for (int it = 0; it < 4; ++it)
            xv[it] = *(const float4*)(xg + (size_t)(k0 + nrow + 16*it)*NSTR + 4*c15);
    };

    loadK(0);
    stage(ldsbuf);
    const unsigned xb = (unsigned)(uintptr_t)ldsbuf;

    for (int kt = 0; kt < 8; ++kt) {
        __syncthreads();
        char* bufC = ldsbuf + (size_t)(kt & 1) * TILE;
        char* bufN = ldsbuf + (size_t)((kt & 1) ^ 1) * TILE;
        if (kt < 7) loadK((kt+1)*64);

        F8 pb[2][2];
        #pragma unroll
        for (int mt = 0; mt < 4; ++mt) {
            float4 av0 = *(const float4*)(arow0 + kt*64 + 16*mt);
            float4 av1 = *(const float4*)(arow1 + kt*64 + 16*mt);
            F8 af0, af1;
            af0.v = *(const s8v*)(bufC + afoff + mt*512);
            af1.v = *(const s8v*)(bufC + afoff + mt*512 + 4096);
            #pragma unroll
            for (int qt = 0; qt < 2; ++qt) {
                f4v sv = (f4v)0.f;
                sv = __builtin_amdgcn_mfma_f32_16x16x32_bf16(af0.v, qf[qt][0].v, sv, 0, 0, 0);
                sv = __builtin_amdgcn_mfma_f32_16x16x32_bf16(af1.v, qf[qt][1].v, sv, 0, 0, 0);
                float e0 = __builtin_amdgcn_exp2f(sv[0] * EXPK);
                float e1 = __builtin_amdgcn_exp2f(sv[1] * EXPK);
                float e2 = __builtin_amdgcn_exp2f(sv[2] * EXPK);
                float e3 = __builtin_amdgcn_exp2f(sv[3] * EXPK);
                l_acc[qt] += (e0 + e1) + (e2 + e3);
                float4 av = qt ? av1 : av0;
                pb[qt][mt>>1].u[2*(mt&1)  ] = cvt_pk(e0*av.x, e1*av.y);
                pb[qt][mt>>1].u[2*(mt&1)+1] = cvt_pk(e2*av.z, e3*av.w);
            }
        }

        const unsigned va = xb + (unsigned)((kt & 1) * TILE) + (unsigned)(lane * 8);
        {
            F8 vf0, vf1, vf2, vf3;
            vf0.u2[0] = tr16<   0>(va); vf0.u2[1] = tr16< 512>(va);
            vf1.u2[0] = tr16<2048>(va); vf1.u2[1] = tr16<2560>(va);
            vf2.u2[0] = tr16<4096>(va); vf2.u2[1] = tr16<4608>(va);
            vf3.u2[0] = tr16<6144>(va); vf3.u2[1] = tr16<6656>(va);
            asm volatile("s_waitcnt lgkmcnt(0)" ::: "memory");
            __builtin_amdgcn_sched_barrier(0);
            #pragma unroll
            for (int qt = 0; qt < 2; ++qt) {
                Oacc[0][qt] = __builtin_amdgcn_mfma_f32_16x16x32_bf16(vf0.v, pb[qt][0].v, Oacc[0][qt], 0, 0, 0);
                Oacc[1][qt] = __builtin_amdgcn_mfma_f32_16x16x32_bf16(vf1.v, pb[qt][0].v, Oacc[1][qt], 0, 0, 0);
                Oacc[2][qt] = __builtin_amdgcn_mfma_f32_16x16x32_bf16(vf2.v, pb[qt][0].v, Oacc[2][qt], 0, 0, 0);
                Oacc[3][qt] = __builtin_amdgcn_mfma_f32_16x16x32_bf16(vf3.v, pb[qt][0].v, Oacc[3][qt], 0, 0, 0);
            }
        }
        {
            F8 vf0, vf1, vf2, vf3;
            vf0.u2[0] = tr16<1024>(va); vf0.u2[1] = tr16<1536>(va);
            vf1.u2[0] = tr16<3072>(va); vf1.u2[1] = tr16<3584>(va);
            vf2.u2[0] = tr16<5120>(va); vf2.u2[1] = tr16<5632>(va);
            vf3.u2[0] = tr16<7168>(va); vf3.u2[1] = tr16<7680>(va);
            asm volatile("s_waitcnt lgkmcnt(0)" ::: "memory");
            __builtin_amdgcn_sched_barrier(0);
            #pragma unroll
            for (int qt = 0; qt < 2; ++qt) {
                Oacc[0][qt] = __builtin_amdgcn_mfma_f32_16x16x32_bf16(vf0.v, pb[qt][1].v, Oacc[0][qt], 0, 0, 0);
                Oacc[1][qt] = __builtin_amdgcn_mfma_f32_16x16x32_bf16(vf1.v, pb[qt][1].v, Oacc[1][qt], 0, 0, 0);
                Oacc[2][qt] = __builtin_amdgcn_mfma_f32_16x16x32_bf16(vf2.v, pb[qt][1].v, Oacc[2][qt], 0, 0, 0);
                Oacc[3][qt] = __builtin_amdgcn_mfma_f32_16x16x32_bf16(vf3.v, pb[qt][1].v, Oacc[3][qt], 0, 0, 0);
            }
        }
        if (kt < 7) stage(bufN);
    }

    float inv[2];
    #pragma unroll
    for (int qt = 0; qt < 2; ++qt) {
        float lv = l_acc[qt];
        lv += __shfl_xor(lv, 16);
        lv += __shfl_xor(lv, 32);
        inv[qt] = 0.125f / lv;
    }

    F8 ob[2][2];
    #pragma unroll
    for (int qt = 0; qt < 2; ++qt)
      #pragma unroll
      for (int kk = 0; kk < 2; ++kk) {
        f4v o0 = Oacc[2*kk][qt], o1 = Oacc[2*kk+1][qt];
        ob[qt][kk].u[0] = cvt_pk(o0[0]*inv[qt], o0[1]*inv[qt]);
        ob[qt][kk].u[1] = cvt_pk(o0[2]*inv[qt], o0[3]*inv[qt]);
        ob[qt][kk].u[2] = cvt_pk(o1[0]*inv[qt], o1[1]*inv[qt]);
        ob[qt][kk].u[3] = cvt_pk(o1[2]*inv[qt], o1[3]*inv[qt]);
      }

    F8 tf[4][2];
    #pragma unroll
    for (int ot = 0; ot < 4; ++ot)
      #pragma unroll
      for (int kk = 0; kk < 2; ++kk) {
        const float* tp2 = theta + (size_t)(16*ot + c15)*F_ + 32*kk + 4*g4;
        float4 a = *(const float4*)tp2;
        float4 c = *(const float4*)(tp2 + 16);
        tf[ot][kk].u[0] = cvt_pk(a.x, a.y);
        tf[ot][kk].u[1] = cvt_pk(a.z, a.w);
        tf[ot][kk].u[2] = cvt_pk(c.x, c.y);
        tf[ot][kk].u[3] = cvt_pk(c.z, c.w);
      }

    f4v R[4][2];
    #pragma unroll
    for (int ot = 0; ot < 4; ++ot)
      #pragma unroll
      for (int qt = 0; qt < 2; ++qt) R[ot][qt] = (f4v)0.f;

    #pragma unroll
    for (int kk = 0; kk < 2; ++kk)
      #pragma unroll
      for (int ot = 0; ot < 4; ++ot)
        #pragma unroll
        for (int qt = 0; qt < 2; ++qt)
          R[ot][qt] = __builtin_amdgcn_mfma_f32_16x16x32_bf16(tf[ot][kk].v, ob[qt][kk].v, R[ot][qt], 0, 0, 0);

    #pragma unroll
    for (int ot = 0; ot < 4; ++ot)
      #pragma unroll
      for (int qt = 0; qt < 2; ++qt) {
        float4 v;
        v.x = fmaxf(R[ot][qt][0], 0.f);
        v.y = fmaxf(R[ot][qt][1], 0.f);
        v.z = fmaxf(R[ot][qt][2], 0.f);
        v.w = fmaxf(R[ot][qt][3], 0.f);
        int q  = q0 + 16*qt + c15;
        int fo = 16*ot + 4*g4;
        *(float4*)(out + ((size_t)(b*N_ + q)*T_ + t)*F_ + fo) = v;
      }
}

extern "C" void kernel_launch(void* const* d_in, const int* in_sizes, int n_in,
                              void* d_out, int out_size, void* d_ws, size_t ws_size,
                              hipStream_t stream) {
    const float* x     = (const float*)d_in[0];
    const float* adj   = (const float*)d_in[1];
    const float* theta = (const float*)d_in[2];
    float* out = (float*)d_out;

    const size_t need = (size_t)B_*T_*N_*F_*2;   // 33.5 MB bf16 xt
    if (ws_size >= need) {
        unsigned short* xt = (unsigned short*)d_ws;
        xpose_kernel<<<dim3(N_/8, T_/32, B_), 256, 0, stream>>>(x, xt);
        sgcn_shadj_kernel<<<1024, 512, 0, stream>>>(xt, adj, theta, out);
    } else {
        dim3 grid(N_ / QB, B_ * T_);
        sgcn_fb_kernel<<<grid, 256, 0, stream>>>(x, adj, theta, out);
    }
}

// Round 11
// 89.116 us; speedup vs baseline: 2.4251x; 1.4731x over previous
//
#include <hip/hip_runtime.h>
#include <math.h>

#define B_   4
#define N_   512
#define T_   128
#define F_   64
#define QB   128       // q rows per block
#define NSTR (T_*F_)   // 8192 floats between consecutive n in x
#define TILE 8192      // bytes per K tile (blocked layout)
// blocked K-tile layout: byte(n,f) = (f>>4)*2048 + (n>>2)*128 + (n&3)*32 + (f&15)*2

typedef __attribute__((ext_vector_type(8))) short  s8v;
typedef __attribute__((ext_vector_type(4))) float  f4v;

union F8 { s8v v; unsigned u[4]; uint2 u2[2]; };

__device__ __forceinline__ unsigned cvt_pk(float lo, float hi) {
    unsigned r;
    asm("v_cvt_pk_bf16_f32 %0, %1, %2" : "=v"(r) : "v"(lo), "v"(hi));
    return r;
}

template<int OFF>
__device__ __forceinline__ uint2 tr16(unsigned a) {
    uint2 d;
    asm volatile("ds_read_b64_tr_b16 %0, %1 offset:%2" : "=v"(d) : "v"(a), "i"(OFF));
    return d;
}

__device__ __forceinline__ void gload16(const void* g, void* l) {
    __builtin_amdgcn_global_load_lds(
        (const __attribute__((address_space(1))) void*)g,
        (__attribute__((address_space(3))) void*)l, 16, 0, 0);
}

#define EXPK 0.18033688f   // 0.125 * log2(e)

// ---- P1: x[b][n][t][f] (f32) -> xt[b][t][n][f] (bf16)  (validated R8) ----
__global__ __launch_bounds__(256)
void xpose_kernel(const float* __restrict__ x, unsigned short* __restrict__ xt)
{
    __shared__ char lds[32*1024];

    const int tid = threadIdx.x;
    const int lane = tid & 63;
    const int w    = tid >> 6;
    const int n0 = blockIdx.x * 8;
    const int t0 = blockIdx.y * 32;
    const int b  = blockIdx.z;

    const int tA = tid >> 3;
    const int f0 = (tid & 7) * 8;

    #pragma unroll
    for (int np = 0; np < 8; ++np) {
        const float* gp = x + ((size_t)(b*N_ + n0 + np)*T_ + t0 + tA)*F_ + f0;
        float4 a = *(const float4*)gp;
        float4 c = *(const float4*)(gp + 4);
        uint4 u;
        u.x = cvt_pk(a.x, a.y); u.y = cvt_pk(a.z, a.w);
        u.z = cvt_pk(c.x, c.y); u.w = cvt_pk(c.z, c.w);
        *(uint4*)(lds + tA*1024 + np*128 + ((f0*2) ^ ((tA & 7) << 4))) = u;
    }
    __syncthreads();

    #pragma unroll
    for (int p = 0; p < 8; ++p) {
        int t  = p*4 + w;
        int np = lane >> 3;
        int i  = lane & 7;
        uint4 u = *(const uint4*)(lds + t*1024 + np*128 + ((i*16) ^ ((t & 7) << 4)));
        *(uint4*)(xt + ((size_t)(b*T_ + t0 + t)*N_ + n0 + np)*F_ + i*8) = u;
    }
}

// ---- main: 2 groups/block share one LDS adj tile; ALL staging via global_load_lds ----
__global__ __launch_bounds__(512, 4)
void sgcn_shadj2_kernel(const unsigned short* __restrict__ xt,
                        const float* __restrict__ adj,
                        const float* __restrict__ theta,
                        float* __restrict__ out)
{
    __shared__ char lds[65536];   // [0,32K): K tiles (2 streams x dbuf x 8K); [32K,64K): adj tile (f32)

    const int tid  = threadIdx.x;
    const int lane = tid & 63;
    const int w    = tid >> 6;     // 0..7
    const int s    = w >> 2;       // stream (group) 0/1
    const int wq   = w & 3;        // q sub-tile within block
    const int c15  = lane & 15;
    const int g4   = lane >> 4;

    const int bid = blockIdx.x;    // 0..1023
    const int qx  = bid & 3;
    const int tp  = bid >> 2;
    const int g   = 2*tp + s;      // this wave's group
    const int b   = g >> 7;
    const int t   = g & 127;
    const int qb  = qx*QB;
    const int q0  = qb + 32*wq;

    const unsigned short* xtg = xt + (size_t)g*N_*F_;
    char* Kbase = lds + s*(2*TILE);
    char* Abase = lds + 32768;

    // ---- Q B-frags (swapped QK): f = 32kk + 8g4 + j ----
    F8 qf[2][2];
    #pragma unroll
    for (int qt = 0; qt < 2; ++qt)
      #pragma unroll
      for (int kk = 0; kk < 2; ++kk)
        qf[qt][kk].v = *(const s8v*)(xtg + (size_t)(q0 + 16*qt + c15)*F_ + 32*kk + 8*g4);

    f4v  Oacc[4][2];
    float l_acc[2] = {0.f, 0.f};
    #pragma unroll
    for (int ft = 0; ft < 4; ++ft)
      #pragma unroll
      for (int qt = 0; qt < 2; ++qt) Oacc[ft][qt] = (f4v)0.f;

    // K gload source offsets (chunk -> (n,f0) of blocked layout; validated R10)
    int soff[2];
    #pragma unroll
    for (int i = 0; i < 2; ++i) {
        int c  = wq*128 + i*64 + lane;
        int fh = c >> 7, r = c & 127;
        int nh = r >> 3, r2 = r & 7;
        soff[i] = (nh*4 + (r2 >> 1))*F_ + fh*16 + (r2 & 1)*8;
    }

    // adj gload source offsets, pre-swizzled (m173): LDS slot (row, c16slot=lane&15)
    // holds source col16 = c16slot ^ (row&15);  layout byte(r,c16)=r*256+((c16^(r&15))<<4)
    int aoff[4];
    #pragma unroll
    for (int j = 0; j < 4; ++j) {
        int row = j*32 + w*4 + (lane >> 4);
        aoff[j] = (qb + row)*N_ + ((c15 ^ (row & 15)) << 2);
    }

    auto stageK = [&](int kt1, int p) {
        const unsigned short* sb = xtg + (size_t)kt1*64*F_;
        #pragma unroll
        for (int i = 0; i < 2; ++i)
            gload16(sb + soff[i], Kbase + p*TILE + (wq*128 + i*64)*16);
    };
    auto stageA = [&](int kt1) {
        #pragma unroll
        for (int j = 0; j < 4; ++j)
            gload16(adj + aoff[j] + kt1*64, Abase + j*8192 + w*1024);
    };

    // QK A-frag byte addr: afoff + mt*512 + kk*4096 -> m = 16mt+c15, f = 32kk+8g4+j
    const int afoff = (g4>>1)*2048 + (c15>>2)*128 + (c15&3)*32 + (g4&1)*16;

    // ---- prologue ----
    stageK(0, 0);
    stageA(0);

    for (int kt = 0; kt < 8; ++kt) {
        __syncthreads();   // vmcnt drained by compiler: K[kt] + adj[kt] resident

        const char* bufC = Kbase + (size_t)(kt & 1)*TILE;
        if (kt < 7) stageK(kt+1, (kt+1) & 1);   // async, other buffer

        // ---- QK^T + softmax (adj f32 from shared LDS tile) ----
        F8 pb[2][2];   // slot j: m = 32kk + 16*(j>=4) + 4g4 + (j&3)
        #pragma unroll
        for (int mt = 0; mt < 4; ++mt) {
            F8 af0, af1;
            af0.v = *(const s8v*)(bufC + afoff + mt*512);
            af1.v = *(const s8v*)(bufC + afoff + mt*512 + 4096);

            #pragma unroll
            for (int qt = 0; qt < 2; ++qt) {
                const int r = 32*wq + 16*qt + c15;
                float4 av = *(const float4*)(Abase + r*256 + ((((mt<<2)+g4) ^ c15) << 4));
                f4v sv = (f4v)0.f;
                sv = __builtin_amdgcn_mfma_f32_16x16x32_bf16(af0.v, qf[qt][0].v, sv, 0, 0, 0);
                sv = __builtin_amdgcn_mfma_f32_16x16x32_bf16(af1.v, qf[qt][1].v, sv, 0, 0, 0);
                float e0 = __builtin_amdgcn_exp2f(sv[0] * EXPK);
                float e1 = __builtin_amdgcn_exp2f(sv[1] * EXPK);
                float e2 = __builtin_amdgcn_exp2f(sv[2] * EXPK);
                float e3 = __builtin_amdgcn_exp2f(sv[3] * EXPK);
                l_acc[qt] += (e0 + e1) + (e2 + e3);
                pb[qt][mt>>1].u[2*(mt&1)  ] = cvt_pk(e0*av.x, e1*av.y);
                pb[qt][mt>>1].u[2*(mt&1)+1] = cvt_pk(e2*av.z, e3*av.w);
            }
        }

        __syncthreads();              // all waves done reading adj[kt]
        if (kt < 7) stageA(kt+1);     // async; lands before next top barrier

        // ---- PV via hardware transpose reads (layout validated R8) ----
        const unsigned va = (unsigned)(uintptr_t)bufC + (unsigned)(lane * 8);
        {
            F8 vf0, vf1, vf2, vf3;
            vf0.u2[0] = tr16<   0>(va); vf0.u2[1] = tr16< 512>(va);
            vf1.u2[0] = tr16<2048>(va); vf1.u2[1] = tr16<2560>(va);
            vf2.u2[0] = tr16<4096>(va); vf2.u2[1] = tr16<4608>(va);
            vf3.u2[0] = tr16<6144>(va); vf3.u2[1] = tr16<6656>(va);
            asm volatile("s_waitcnt lgkmcnt(0)" ::: "memory");
            __builtin_amdgcn_sched_barrier(0);
            #pragma unroll
            for (int qt = 0; qt < 2; ++qt) {
                Oacc[0][qt] = __builtin_amdgcn_mfma_f32_16x16x32_bf16(vf0.v, pb[qt][0].v, Oacc[0][qt], 0, 0, 0);
                Oacc[1][qt] = __builtin_amdgcn_mfma_f32_16x16x32_bf16(vf1.v, pb[qt][0].v, Oacc[1][qt], 0, 0, 0);
                Oacc[2][qt] = __builtin_amdgcn_mfma_f32_16x16x32_bf16(vf2.v, pb[qt][0].v, Oacc[2][qt], 0, 0, 0);
                Oacc[3][qt] = __builtin_amdgcn_mfma_f32_16x16x32_bf16(vf3.v, pb[qt][0].v, Oacc[3][qt], 0, 0, 0);
            }
        }
        {
            F8 vf0, vf1, vf2, vf3;
            vf0.u2[0] = tr16<1024>(va); vf0.u2[1] = tr16<1536>(va);
            vf1.u2[0] = tr16<3072>(va); vf1.u2[1] = tr16<3584>(va);
            vf2.u2[0] = tr16<5120>(va); vf2.u2[1] = tr16<5632>(va);
            vf3.u2[0] = tr16<7168>(va); vf3.u2[1] = tr16<7680>(va);
            asm volatile("s_waitcnt lgkmcnt(0)" ::: "memory");
            __builtin_amdgcn_sched_barrier(0);
            #pragma unroll
            for (int qt = 0; qt < 2; ++qt) {
                Oacc[0][qt] = __builtin_amdgcn_mfma_f32_16x16x32_bf16(vf0.v, pb[qt][1].v, Oacc[0][qt], 0, 0, 0);
                Oacc[1][qt] = __builtin_amdgcn_mfma_f32_16x16x32_bf16(vf1.v, pb[qt][1].v, Oacc[1][qt], 0, 0, 0);
                Oacc[2][qt] = __builtin_amdgcn_mfma_f32_16x16x32_bf16(vf2.v, pb[qt][1].v, Oacc[2][qt], 0, 0, 0);
                Oacc[3][qt] = __builtin_amdgcn_mfma_f32_16x16x32_bf16(vf3.v, pb[qt][1].v, Oacc[3][qt], 0, 0, 0);
            }
        }
    }

    // ---- softmax denominators ----
    float inv[2];
    #pragma unroll
    for (int qt = 0; qt < 2; ++qt) {
        float lv = l_acc[qt];
        lv += __shfl_xor(lv, 16);
        lv += __shfl_xor(lv, 32);
        inv[qt] = 0.125f / lv;
    }

    // ---- B-frags from O^T (lane-local), scaled ----
    F8 ob[2][2];
    #pragma unroll
    for (int qt = 0; qt < 2; ++qt)
      #pragma unroll
      for (int kk = 0; kk < 2; ++kk) {
        f4v o0 = Oacc[2*kk][qt], o1 = Oacc[2*kk+1][qt];
        ob[qt][kk].u[0] = cvt_pk(o0[0]*inv[qt], o0[1]*inv[qt]);
        ob[qt][kk].u[1] = cvt_pk(o0[2]*inv[qt], o0[3]*inv[qt]);
        ob[qt][kk].u[2] = cvt_pk(o1[0]*inv[qt], o1[1]*inv[qt]);
        ob[qt][kk].u[3] = cvt_pk(o1[2]*inv[qt], o1[3]*inv[qt]);
      }

    // ---- Theta A-frags ----
    F8 tf[4][2];
    #pragma unroll
    for (int ot = 0; ot < 4; ++ot)
      #pragma unroll
      for (int kk = 0; kk < 2; ++kk) {
        const float* tp2 = theta + (size_t)(16*ot + c15)*F_ + 32*kk + 4*g4;
        float4 a = *(const float4*)tp2;
        float4 c = *(const float4*)(tp2 + 16);
        tf[ot][kk].u[0] = cvt_pk(a.x, a.y);
        tf[ot][kk].u[1] = cvt_pk(a.z, a.w);
        tf[ot][kk].u[2] = cvt_pk(c.x, c.y);
        tf[ot][kk].u[3] = cvt_pk(c.z, c.w);
      }

    // ---- R^T = Theta * (O^T * inv), relu, store ----
    f4v R[4][2];
    #pragma unroll
    for (int ot = 0; ot < 4; ++ot)
      #pragma unroll
      for (int qt = 0; qt < 2; ++qt) R[ot][qt] = (f4v)0.f;

    #pragma unroll
    for (int kk = 0; kk < 2; ++kk)
      #pragma unroll
      for (int ot = 0; ot < 4; ++ot)
        #pragma unroll
        for (int qt = 0; qt < 2; ++qt)
          R[ot][qt] = __builtin_amdgcn_mfma_f32_16x16x32_bf16(tf[ot][kk].v, ob[qt][kk].v, R[ot][qt], 0, 0, 0);

    #pragma unroll
    for (int ot = 0; ot < 4; ++ot)
      #pragma unroll
      for (int qt = 0; qt < 2; ++qt) {
        float4 v;
        v.x = fmaxf(R[ot][qt][0], 0.f);
        v.y = fmaxf(R[ot][qt][1], 0.f);
        v.z = fmaxf(R[ot][qt][2], 0.f);
        v.w = fmaxf(R[ot][qt][3], 0.f);
        int q  = q0 + 16*qt + c15;
        int fo = 16*ot + 4*g4;
        *(float4*)(out + ((size_t)(b*N_ + q)*T_ + t)*F_ + fo) = v;
      }
}

// ---- fallback (R8 kernel, self-contained, validated) ----
__global__ __launch_bounds__(256, 3)
void sgcn_fb_kernel(const float* __restrict__ x,
                    const float* __restrict__ adj,
                    const float* __restrict__ theta,
                    float* __restrict__ out)
{
    __shared__ char ldsbuf[2*TILE];

    const int tid  = threadIdx.x;
    const int lane = tid & 63;
    const int w    = tid >> 6;
    const int c15  = lane & 15;
    const int g4   = lane >> 4;

    const int g  = blockIdx.y;
    const int b  = g >> 7;
    const int t  = g & 127;
    const int q0 = blockIdx.x*QB + 32*w;

    const float* xg = x + (size_t)b*N_*NSTR + (size_t)t*F_;

    F8 qf[2][2];
    #pragma unroll
    for (int qt = 0; qt < 2; ++qt)
      #pragma unroll
      for (int kk = 0; kk < 2; ++kk) {
        const float* qp = xg + (size_t)(q0 + 16*qt + c15)*NSTR + 32*kk + 8*g4;
        float4 a = *(const float4*)qp;
        float4 c = *(const float4*)(qp + 4);
        qf[qt][kk].u[0] = cvt_pk(a.x, a.y);
        qf[qt][kk].u[1] = cvt_pk(a.z, a.w);
        qf[qt][kk].u[2] = cvt_pk(c.x, c.y);
        qf[qt][kk].u[3] = cvt_pk(c.z, c.w);
      }

    f4v  Oacc[4][2];
    float l_acc[2] = {0.f, 0.f};
    #pragma unroll
    for (int ft = 0; ft < 4; ++ft)
      #pragma unroll
      for (int qt = 0; qt < 2; ++qt) Oacc[ft][qt] = (f4v)0.f;

    const int nrow  = tid >> 4;
    const int stoff = (c15>>2)*2048 + w*128 + g4*32 + (c15&3)*8;
    const int afoff = (g4>>1)*2048 + (c15>>2)*128 + (c15&3)*32 + (g4&1)*16;

    const float* arow0 = adj + (size_t)(q0 +      c15)*N_ + 4*g4;
    const float* arow1 = adj + (size_t)(q0 + 16 + c15)*N_ + 4*g4;

    float4 xv[4];
    auto stage = [&](char* buf) {
        #pragma unroll
        for (int it = 0; it < 4; ++it) {
            unsigned p0 = cvt_pk(xv[it].x, xv[it].y);
            unsigned p1 = cvt_pk(xv[it].z, xv[it].w);
            *(uint2*)(buf + stoff + it*512) = make_uint2(p0, p1);
        }
    };
    auto loadK = [&](int k0) {
        #pragma unroll
        for (int it = 0; it < 4; ++it)
            xv[it] = *(const float4*)(xg + (size_t)(k0 + nrow + 16*it)*NSTR + 4*c15);
    };

    loadK(0);
    stage(ldsbuf);
    const unsigned xb = (unsigned)(uintptr_t)ldsbuf;

    for (int kt = 0; kt < 8; ++kt) {
        __syncthreads();
        char* bufC = ldsbuf + (size_t)(kt & 1) * TILE;
        char* bufN = ldsbuf + (size_t)((kt & 1) ^ 1) * TILE;
        if (kt < 7) loadK((kt+1)*64);

        F8 pb[2][2];
        #pragma unroll
        for (int mt = 0; mt < 4; ++mt) {
            float4 av0 = *(const float4*)(arow0 + kt*64 + 16*mt);
            float4 av1 = *(const float4*)(arow1 + kt*64 + 16*mt);
            F8 af0, af1;
            af0.v = *(const s8v*)(bufC + afoff + mt*512);
            af1.v = *(const s8v*)(bufC + afoff + mt*512 + 4096);
            #pragma unroll
            for (int qt = 0; qt < 2; ++qt) {
                f4v sv = (f4v)0.f;
                sv = __builtin_amdgcn_mfma_f32_16x16x32_bf16(af0.v, qf[qt][0].v, sv, 0, 0, 0);
                sv = __builtin_amdgcn_mfma_f32_16x16x32_bf16(af1.v, qf[qt][1].v, sv, 0, 0, 0);
                float e0 = __builtin_amdgcn_exp2f(sv[0] * EXPK);
                float e1 = __builtin_amdgcn_exp2f(sv[1] * EXPK);
                float e2 = __builtin_amdgcn_exp2f(sv[2] * EXPK);
                float e3 = __builtin_amdgcn_exp2f(sv[3] * EXPK);
                l_acc[qt] += (e0 + e1) + (e2 + e3);
                float4 av = qt ? av1 : av0;
                pb[qt][mt>>1].u[2*(mt&1)  ] = cvt_pk(e0*av.x, e1*av.y);
                pb[qt][mt>>1].u[2*(mt&1)+1] = cvt_pk(e2*av.z, e3*av.w);
            }
        }

        const unsigned va = xb + (unsigned)((kt & 1) * TILE) + (unsigned)(lane * 8);
        {
            F8 vf0, vf1, vf2, vf3;
            vf0.u2[0] = tr16<   0>(va); vf0.u2[1] = tr16< 512>(va);
            vf1.u2[0] = tr16<2048>(va); vf1.u2[1] = tr16<2560>(va);
            vf2.u2[0] = tr16<4096>(va); vf2.u2[1] = tr16<4608>(va);
            vf3.u2[0] = tr16<6144>(va); vf3.u2[1] = tr16<6656>(va);
            asm volatile("s_waitcnt lgkmcnt(0)" ::: "memory");
            __builtin_amdgcn_sched_barrier(0);
            #pragma unroll
            for (int qt = 0; qt < 2; ++qt) {
                Oacc[0][qt] = __builtin_amdgcn_mfma_f32_16x16x32_bf16(vf0.v, pb[qt][0].v, Oacc[0][qt], 0, 0, 0);
                Oacc[1][qt] = __builtin_amdgcn_mfma_f32_16x16x32_bf16(vf1.v, pb[qt][0].v, Oacc[1][qt], 0, 0, 0);
                Oacc[2][qt] = __builtin_amdgcn_mfma_f32_16x16x32_bf16(vf2.v, pb[qt][0].v, Oacc[2][qt], 0, 0, 0);
                Oacc[3][qt] = __builtin_amdgcn_mfma_f32_16x16x32_bf16(vf3.v, pb[qt][0].v, Oacc[3][qt], 0, 0, 0);
            }
        }
        {
            F8 vf0, vf1, vf2, vf3;
            vf0.u2[0] = tr16<1024>(va); vf0.u2[1] = tr16<1536>(va);
            vf1.u2[0] = tr16<3072>(va); vf1.u2[1] = tr16<3584>(va);
            vf2.u2[0] = tr16<5120>(va); vf2.u2[1] = tr16<5632>(va);
            vf3.u2[0] = tr16<7168>(va); vf3.u2[1] = tr16<7680>(va);
            asm volatile("s_waitcnt lgkmcnt(0)" ::: "memory");
            __builtin_amdgcn_sched_barrier(0);
            #pragma unroll
            for (int qt = 0; qt < 2; ++qt) {
                Oacc[0][qt] = __builtin_amdgcn_mfma_f32_16x16x32_bf16(vf0.v, pb[qt][1].v, Oacc[0][qt], 0, 0, 0);
                Oacc[1][qt] = __builtin_amdgcn_mfma_f32_16x16x32_bf16(vf1.v, pb[qt][1].v, Oacc[1][qt], 0, 0, 0);
                Oacc[2][qt] = __builtin_amdgcn_mfma_f32_16x16x32_bf16(vf2.v, pb[qt][1].v, Oacc[2][qt], 0, 0, 0);
                Oacc[3][qt] = __builtin_amdgcn_mfma_f32_16x16x32_bf16(vf3.v, pb[qt][1].v, Oacc[3][qt], 0, 0, 0);
            }
        }
        if (kt < 7) stage(bufN);
    }

    float inv[2];
    #pragma unroll
    for (int qt = 0; qt < 2; ++qt) {
        float lv = l_acc[qt];
        lv += __shfl_xor(lv, 16);
        lv += __shfl_xor(lv, 32);
        inv[qt] = 0.125f / lv;
    }

    F8 ob[2][2];
    #pragma unroll
    for (int qt = 0; qt < 2; ++qt)
      #pragma unroll
      for (int kk = 0; kk < 2; ++kk) {
        f4v o0 = Oacc[2*kk][qt], o1 = Oacc[2*kk+1][qt];
        ob[qt][kk].u[0] = cvt_pk(o0[0]*inv[qt], o0[1]*inv[qt]);
        ob[qt][kk].u[1] = cvt_pk(o0[2]*inv[qt], o0[3]*inv[qt]);
        ob[qt][kk].u[2] = cvt_pk(o1[0]*inv[qt], o1[1]*inv[qt]);
        ob[qt][kk].u[3] = cvt_pk(o1[2]*inv[qt], o1[3]*inv[qt]);
      }

    F8 tf[4][2];
    #pragma unroll
    for (int ot = 0; ot < 4; ++ot)
      #pragma unroll
      for (int kk = 0; kk < 2; ++kk) {
        const float* tp2 = theta + (size_t)(16*ot + c15)*F_ + 32*kk + 4*g4;
        float4 a = *(const float4*)tp2;
        float4 c = *(const float4*)(tp2 + 16);
        tf[ot][kk].u[0] = cvt_pk(a.x, a.y);
        tf[ot][kk].u[1] = cvt_pk(a.z, a.w);
        tf[ot][kk].u[2] = cvt_pk(c.x, c.y);
        tf[ot][kk].u[3] = cvt_pk(c.z, c.w);
      }

    f4v R[4][2];
    #pragma unroll
    for (int ot = 0; ot < 4; ++ot)
      #pragma unroll
      for (int qt = 0; qt < 2; ++qt) R[ot][qt] = (f4v)0.f;

    #pragma unroll
    for (int kk = 0; kk < 2; ++kk)
      #pragma unroll
      for (int ot = 0; ot < 4; ++ot)
        #pragma unroll
        for (int qt = 0; qt < 2; ++qt)
          R[ot][qt] = __builtin_amdgcn_mfma_f32_16x16x32_bf16(tf[ot][kk].v, ob[qt][kk].v, R[ot][qt], 0, 0, 0);

    #pragma unroll
    for (int ot = 0; ot < 4; ++ot)
      #pragma unroll
      for (int qt = 0; qt < 2; ++qt) {
        float4 v;
        v.x = fmaxf(R[ot][qt][0], 0.f);
        v.y = fmaxf(R[ot][qt][1], 0.f);
        v.z = fmaxf(R[ot][qt][2], 0.f);
        v.w = fmaxf(R[ot][qt][3], 0.f);
        int q  = q0 + 16*qt + c15;
        int fo = 16*ot + 4*g4;
        *(float4*)(out + ((size_t)(b*N_ + q)*T_ + t)*F_ + fo) = v;
      }
}

extern "C" void kernel_launch(void* const* d_in, const int* in_sizes, int n_in,
                              void* d_out, int out_size, void* d_ws, size_t ws_size,
                              hipStream_t stream) {
    const float* x     = (const float*)d_in[0];
    const float* adj   = (const float*)d_in[1];
    const float* theta = (const float*)d_in[2];
    float* out = (float*)d_out;

    const size_t need = (size_t)B_*T_*N_*F_*2;   // 33.5 MB bf16 xt
    if (ws_size >= need) {
        unsigned short* xt = (unsigned short*)d_ws;
        xpose_kernel<<<dim3(N_/8, T_/32, B_), 256, 0, stream>>>(x, xt);
        sgcn_shadj2_kernel<<<1024, 512, 0, stream>>>(xt, adj, theta, out);
    } else {
        dim3 grid(N_ / QB, B_ * T_);
        sgcn_fb_kernel<<<grid, 256, 0, stream>>>(x, adj, theta, out);
    }
}